// Round 8
// baseline (89.768 us; speedup 1.0000x reference)
//
#include <hip/hip_runtime.h>
#include <math.h>

#define FIN   64
#define NK    512
#define FOUT  256
#define BB    16
#define NTHR  512
#define RSTRH 520   // ushort stride: 1040B row = 65*16B, 16B-aligned, 2-way max bank

typedef __attribute__((ext_vector_type(8))) short short8;
typedef __attribute__((ext_vector_type(4))) float f32x4;
typedef unsigned short ushort_t;

#define MFMA(a, b, c) __builtin_amdgcn_mfma_f32_16x16x32_bf16((a), (b), (c), 0, 0, 0)

// ---- ws layout (ushort element offsets; all 16B-aligned) ----
#define XHI   0
#define XMID  262144
#define XLO   524288
#define CHI   786432
#define CMID  819200
#define CLO   851968
#define WHI   884736
#define WLO   1015808
#define USH_END 1146880          // *2B = 2,293,760 B (16B-aligned)
// float section (fs = (float*)(us + USH_END)):
#define CSQ_F 0
#define E2_F  512
#define XSQ_F 1024               // 4096 entries; float end = 5120

__device__ __forceinline__ ushort_t top16(float f) {
    return (ushort_t)(__builtin_bit_cast(unsigned, f) >> 16);
}
__device__ __forceinline__ float fromtop(ushort_t h) {
    return __builtin_bit_cast(float, ((unsigned)h) << 16);
}
__device__ __forceinline__ float trunc_bf(float f) {
    return __builtin_bit_cast(float, __builtin_bit_cast(unsigned, f) & 0xFFFF0000u);
}

// ---------------- prep: all conversions, once per launch ----------------
__global__ __launch_bounds__(256) void rbf_prep_kernel(
    const float* __restrict__ x, const float* __restrict__ w,
    const float* __restrict__ cent, const float* __restrict__ ls,
    ushort_t* __restrict__ us, float* __restrict__ fs)
{
    const int gid = blockIdx.x * 256 + threadIdx.x;
    const int nth = gridDim.x * 256;

    for (int i = gid; i < 4096 * FIN; i += nth) {        // x: 3-split
        const float v = x[i];
        const float m1 = v - trunc_bf(v);
        const float l1 = m1 - trunc_bf(m1);
        us[XHI + i]  = top16(v);
        us[XMID + i] = top16(m1);
        us[XLO + i]  = top16(l1);
    }
    for (int i = gid; i < NK * FIN; i += nth) {          // cent: 3-split
        const float v = cent[i];
        const float m1 = v - trunc_bf(v);
        const float l1 = m1 - trunc_bf(m1);
        us[CHI + i]  = top16(v);
        us[CMID + i] = top16(m1);
        us[CLO + i]  = top16(l1);
    }
    for (int i = gid; i < FOUT * NK; i += nth) {         // w: 2-split
        const float v = w[i];
        const float l1 = v - trunc_bf(v);
        us[WHI + i] = top16(v);
        us[WLO + i] = top16(l1);
    }
    for (int r = gid; r < 4096; r += nth) {              // xsq (exact f32)
        const float4* xp = (const float4*)(x + (size_t)r * FIN);
        float s = 0.f;
        #pragma unroll
        for (int j = 0; j < 16; ++j) {
            const float4 c = xp[j];
            s = fmaf(c.x, c.x, s); s = fmaf(c.y, c.y, s);
            s = fmaf(c.z, c.z, s); s = fmaf(c.w, c.w, s);
        }
        fs[XSQ_F + r] = s;
    }
    for (int k = gid; k < NK; k += nth) {                // csq + e2
        const float4* cp = (const float4*)(cent + (size_t)k * FIN);
        float s = 0.f;
        #pragma unroll
        for (int j = 0; j < 16; ++j) {
            const float4 c = cp[j];
            s = fmaf(c.x, c.x, s); s = fmaf(c.y, c.y, s);
            s = fmaf(c.z, c.z, s); s = fmaf(c.w, c.w, s);
        }
        fs[CSQ_F + k] = s;
        fs[E2_F + k]  = __expf(2.f * ls[k]);
    }
}

// ---------------- main: pure MFMA + exp ----------------
__global__ __launch_bounds__(NTHR, 2) void rbf_main_kernel(
    const ushort_t* __restrict__ us, const float* __restrict__ fs,
    float* __restrict__ out)
{
    __shared__ __align__(16) ushort_t RsHi[BB][RSTRH];   // 16.6 KB
    __shared__ __align__(16) ushort_t RsLo[BB][RSTRH];   // 16.6 KB
    __shared__ float rowpart[8][BB];
    __shared__ float invs[BB];

    const int tid   = threadIdx.x;
    const int lane  = tid & 63;
    const int wv    = tid >> 6;       // 8 waves
    const int arow  = lane & 15;
    const int dg    = lane >> 4;      // 0..3
    const int d0    = dg * 8;
    const int rbase = dg * 4;
    const int b0    = blockIdx.x * BB;

    // A-fragments: pre-split x, rows b0+arow, dims [d0,d0+8) and [32+d0,...)
    const int xoff = (b0 + arow) * FIN;
    const short8 ax1_0 = *(const short8*)&us[XHI  + xoff + d0];
    const short8 ax1_1 = *(const short8*)&us[XHI  + xoff + 32 + d0];
    const short8 ax2_0 = *(const short8*)&us[XMID + xoff + d0];
    const short8 ax2_1 = *(const short8*)&us[XMID + xoff + 32 + d0];
    const short8 ax3_0 = *(const short8*)&us[XLO  + xoff + d0];
    const short8 ax3_1 = *(const short8*)&us[XLO  + xoff + 32 + d0];

    const float xq0 = fs[XSQ_F + b0 + rbase + 0];
    const float xq1 = fs[XSQ_F + b0 + rbase + 1];
    const float xq2 = fs[XSQ_F + b0 + rbase + 2];
    const float xq3 = fs[XSQ_F + b0 + rbase + 3];

    // ---- phase 2: cross = X C^T (3-split MFMA), fused rbf ----
    float ps0 = 0.f, ps1 = 0.f, ps2 = 0.f, ps3 = 0.f;
    #pragma unroll 1
    for (int i = 0; i < 4; ++i) {
        const int n0  = 64 * wv + 16 * i;
        const int col = n0 + arow;
        const int coff = col * FIN;
        const short8 b1_0 = *(const short8*)&us[CHI  + coff + d0];
        const short8 b1_1 = *(const short8*)&us[CHI  + coff + 32 + d0];
        const short8 b2_0 = *(const short8*)&us[CMID + coff + d0];
        const short8 b2_1 = *(const short8*)&us[CMID + coff + 32 + d0];
        const short8 b3_0 = *(const short8*)&us[CLO  + coff + d0];
        const short8 b3_1 = *(const short8*)&us[CLO  + coff + 32 + d0];
        const float cq = fs[CSQ_F + col];
        const float e2 = fs[E2_F + col];

        f32x4 acc = {0.f, 0.f, 0.f, 0.f};
        acc = MFMA(ax1_0, b1_0, acc);
        acc = MFMA(ax1_0, b2_0, acc);
        acc = MFMA(ax2_0, b1_0, acc);
        acc = MFMA(ax2_0, b2_0, acc);
        acc = MFMA(ax1_0, b3_0, acc);
        acc = MFMA(ax3_0, b1_0, acc);
        acc = MFMA(ax1_1, b1_1, acc);
        acc = MFMA(ax1_1, b2_1, acc);
        acc = MFMA(ax2_1, b1_1, acc);
        acc = MFMA(ax2_1, b2_1, acc);
        acc = MFMA(ax1_1, b3_1, acc);
        acc = MFMA(ax3_1, b1_1, acc);

        // C layout: col=lane&15, row=(lane>>4)*4+j  [verified]
        {
            const float ssq = fmaf(-2.f, acc[0], xq0 + cq);
            const float rb = __expf(-(e2 * ssq));
            ps0 += rb;
            RsHi[rbase + 0][col] = top16(rb);
            RsLo[rbase + 0][col] = top16(rb - trunc_bf(rb));
        }
        {
            const float ssq = fmaf(-2.f, acc[1], xq1 + cq);
            const float rb = __expf(-(e2 * ssq));
            ps1 += rb;
            RsHi[rbase + 1][col] = top16(rb);
            RsLo[rbase + 1][col] = top16(rb - trunc_bf(rb));
        }
        {
            const float ssq = fmaf(-2.f, acc[2], xq2 + cq);
            const float rb = __expf(-(e2 * ssq));
            ps2 += rb;
            RsHi[rbase + 2][col] = top16(rb);
            RsLo[rbase + 2][col] = top16(rb - trunc_bf(rb));
        }
        {
            const float ssq = fmaf(-2.f, acc[3], xq3 + cq);
            const float rb = __expf(-(e2 * ssq));
            ps3 += rb;
            RsHi[rbase + 3][col] = top16(rb);
            RsLo[rbase + 3][col] = top16(rb - trunc_bf(rb));
        }
    }
    // fold row partials across the 16 n-lanes
    ps0 += __shfl_xor(ps0, 1); ps0 += __shfl_xor(ps0, 2); ps0 += __shfl_xor(ps0, 4); ps0 += __shfl_xor(ps0, 8);
    ps1 += __shfl_xor(ps1, 1); ps1 += __shfl_xor(ps1, 2); ps1 += __shfl_xor(ps1, 4); ps1 += __shfl_xor(ps1, 8);
    ps2 += __shfl_xor(ps2, 1); ps2 += __shfl_xor(ps2, 2); ps2 += __shfl_xor(ps2, 4); ps2 += __shfl_xor(ps2, 8);
    ps3 += __shfl_xor(ps3, 1); ps3 += __shfl_xor(ps3, 2); ps3 += __shfl_xor(ps3, 4); ps3 += __shfl_xor(ps3, 8);
    if (arow == 0) {
        rowpart[wv][rbase + 0] = ps0;
        rowpart[wv][rbase + 1] = ps1;
        rowpart[wv][rbase + 2] = ps2;
        rowpart[wv][rbase + 3] = ps3;
    }
    __syncthreads();
    if (tid < BB) {
        float s = 0.f;
        #pragma unroll
        for (int q = 0; q < 8; ++q) s += rowpart[q][tid];
        invs[tid] = 1.f / (1e-9f + s);
    }
    __syncthreads();

    // ---- phase 4: out = R W^T (2-split MFMA), pre-split W from L2 ----
    const int c0 = 32 * wv;
    const int w0off = (c0 + arow) * NK;
    const int w1off = (c0 + 16 + arow) * NK;

    f32x4 o0 = {0.f, 0.f, 0.f, 0.f};
    f32x4 o1 = {0.f, 0.f, 0.f, 0.f};
    #pragma unroll 2
    for (int ks = 0; ks < NK / 32; ++ks) {
        const int kb = ks * 32 + d0;
        const short8 ahi = *(const short8*)&RsHi[arow][kb];
        const short8 alo = *(const short8*)&RsLo[arow][kb];
        const short8 w0h = *(const short8*)&us[WHI + w0off + kb];
        const short8 w0l = *(const short8*)&us[WLO + w0off + kb];
        const short8 w1h = *(const short8*)&us[WHI + w1off + kb];
        const short8 w1l = *(const short8*)&us[WLO + w1off + kb];
        o0 = MFMA(ahi, w0h, o0);
        o0 = MFMA(ahi, w0l, o0);
        o0 = MFMA(alo, w0h, o0);
        o1 = MFMA(ahi, w1h, o1);
        o1 = MFMA(ahi, w1l, o1);
        o1 = MFMA(alo, w1h, o1);
    }

    // ---- epilogue ----
    #pragma unroll
    for (int j = 0; j < 4; ++j) {
        const int row = rbase + j;
        const float iv = invs[row];
        out[(size_t)(b0 + row) * FOUT + c0 + arow]      = o0[j] * iv;
        out[(size_t)(b0 + row) * FOUT + c0 + 16 + arow] = o1[j] * iv;
    }
}

extern "C" void kernel_launch(void* const* d_in, const int* in_sizes, int n_in,
                              void* d_out, int out_size, void* d_ws, size_t ws_size,
                              hipStream_t stream) {
    const float* x    = (const float*)d_in[0];   // [4096][64]
    const float* w    = (const float*)d_in[1];   // [256][512]
    const float* cent = (const float*)d_in[2];   // [512][64]
    const float* ls   = (const float*)d_in[3];   // [512]
    float* out        = (float*)d_out;           // [4096][256]

    ushort_t* us = (ushort_t*)d_ws;
    float*    fs = (float*)(us + USH_END);

    rbf_prep_kernel<<<dim3(512), dim3(256), 0, stream>>>(x, w, cent, ls, us, fs);
    rbf_main_kernel<<<dim3(4096 / BB), dim3(NTHR), 0, stream>>>(us, fs, out);
}